// Round 1
// baseline (630.253 us; speedup 1.0000x reference)
//
#include <hip/hip_runtime.h>

#define N_NODES 20000
#define N_EDGES 320000
#define IN_F 256
#define EIN_F 64
#define NH 4
#define HFE 64   // H*FE
#define HFO 256  // H*FO

// K0: out[0:N*256] = x (residual init, scatter target); denom = 0
__global__ void k0_init(const float* __restrict__ x, float* __restrict__ out,
                        float* __restrict__ denom) {
    int stride = gridDim.x * blockDim.x;
    for (int i = blockIdx.x * blockDim.x + threadIdx.x; i < N_NODES * HFO; i += stride)
        out[i] = x[i];
    for (int j = blockIdx.x * blockDim.x + threadIdx.x; j < N_NODES * NH; j += stride)
        denom[j] = 0.f;
}

// K1: fused node GEMM: xni = x@W_ni [N,64], xnj = x@W_nj [N,64], hfeat = x@W_src [N,256]
// block = 384 threads (cols), 8 nodes per block, x rows staged in LDS.
__global__ __launch_bounds__(384) void k1_node_gemm(
    const float* __restrict__ x, const float* __restrict__ Wni,
    const float* __restrict__ Wnj, const float* __restrict__ Wsrc,
    float* __restrict__ xni, float* __restrict__ xnj, float* __restrict__ hfeat)
{
    __shared__ float xs[8][IN_F];
    const int n0 = blockIdx.x * 8;
    const int tid = threadIdx.x; // 0..383
    for (int i = tid; i < 8 * IN_F; i += 384) {
        int r = i >> 8, c = i & 255;
        xs[r][c] = x[(n0 + r) * IN_F + c];
    }
    __syncthreads();
    float acc[8];
#pragma unroll
    for (int i = 0; i < 8; i++) acc[i] = 0.f;

    const float* W;
    int ldw, col;
    if (tid < 64)       { W = Wni;  ldw = 64;  col = tid;       }
    else if (tid < 128) { W = Wnj;  ldw = 64;  col = tid - 64;  }
    else                { W = Wsrc; ldw = 256; col = tid - 128; }

    for (int k = 0; k < IN_F; k++) {
        float w = W[k * ldw + col];
#pragma unroll
        for (int i = 0; i < 8; i++) acc[i] += xs[i][k] * w;
    }

    if (tid < 64) {
#pragma unroll
        for (int i = 0; i < 8; i++) xni[(n0 + i) * 64 + col] = acc[i];
    } else if (tid < 128) {
#pragma unroll
        for (int i = 0; i < 8; i++) xnj[(n0 + i) * 64 + col] = acc[i];
    } else {
#pragma unroll
        for (int i = 0; i < 8; i++) hfeat[(n0 + i) * 256 + col] = acc[i];
    }
}

// K2: per-edge (wave per edge, 4 edges/block):
// f = leaky(efeats@W_fij + xni[src] + xnj[dst] + bias) -> fout;  e = sum16(f*attn) -> escore
__global__ __launch_bounds__(256) void k2_edge(
    const float* __restrict__ efeats, const int* __restrict__ src, const int* __restrict__ dst,
    const float* __restrict__ Wfij, const float* __restrict__ attn, const float* __restrict__ bias,
    const float* __restrict__ xni, const float* __restrict__ xnj,
    float* __restrict__ fout, float* __restrict__ escore)
{
    __shared__ float Wf[64 * 64];
    __shared__ float efs[4][64];
    const int tid = threadIdx.x;
    for (int i = tid; i < 64 * 64; i += 256) Wf[i] = Wfij[i];

    const int w = tid >> 6, lane = tid & 63;
    const long e = (long)blockIdx.x * 4 + w;
    const bool valid = e < N_EDGES;
    if (valid) efs[w][lane] = efeats[e * 64 + lane];
    __syncthreads();
    if (!valid) return;

    float acc = 0.f;
#pragma unroll 8
    for (int k = 0; k < 64; k++) acc += efs[w][k] * Wf[k * 64 + lane];

    const int s = src[e], d = dst[e];
    float f = acc + xni[s * 64 + lane] + xnj[d * 64 + lane] + bias[lane];
    f = (f >= 0.f) ? f : 0.2f * f;
    fout[e * 64 + lane] = f;

    float p = f * attn[lane];           // attn flat [H*FE] matches lane layout
    p += __shfl_xor(p, 1, 64);
    p += __shfl_xor(p, 2, 64);
    p += __shfl_xor(p, 4, 64);
    p += __shfl_xor(p, 8, 64);
    if ((lane & 15) == 0) escore[e * 4 + (lane >> 4)] = p;
}

// K3: ex = exp(e) in place; denom[dst] += ex   (no max-subtract: shift-invariant, |e| small)
__global__ void k3_denom(const int* __restrict__ dst, float* __restrict__ escore,
                         float* __restrict__ denom) {
    int e = blockIdx.x * blockDim.x + threadIdx.x;
    if (e >= N_EDGES) return;
    float4 v = ((const float4*)escore)[e];
    float4 ex;
    ex.x = expf(v.x); ex.y = expf(v.y); ex.z = expf(v.z); ex.w = expf(v.w);
    ((float4*)escore)[e] = ex;
    const int d = dst[e];
    atomicAdd(&denom[d * 4 + 0], ex.x);
    atomicAdd(&denom[d * 4 + 1], ex.y);
    atomicAdd(&denom[d * 4 + 2], ex.z);
    atomicAdd(&denom[d * 4 + 3], ex.w);
}

// K4: wave per edge: a = ex/denom[dst]; out[dst] += a_h * hfeat[src]  (out pre-set to x)
__global__ __launch_bounds__(256) void k4_scatter(
    const int* __restrict__ src, const int* __restrict__ dst,
    const float* __restrict__ escore, const float* __restrict__ denom,
    const float* __restrict__ hfeat, float* __restrict__ out)
{
    const int w = threadIdx.x >> 6, lane = threadIdx.x & 63;
    const long e = (long)blockIdx.x * 4 + w;
    if (e >= N_EDGES) return;
    const int s = src[e], d = dst[e];
    float4 ex = ((const float4*)escore)[e];
    float4 dn = ((const float4*)denom)[d];
    const float a0 = ex.x / dn.x, a1 = ex.y / dn.y, a2 = ex.z / dn.z, a3 = ex.w / dn.w;
    const float* hs = hfeat + (long)s * 256;
    float* od = out + (long)d * 256;
    atomicAdd(&od[lane],       a0 * hs[lane]);
    atomicAdd(&od[64 + lane],  a1 * hs[64 + lane]);
    atomicAdd(&od[128 + lane], a2 * hs[128 + lane]);
    atomicAdd(&od[192 + lane], a3 * hs[192 + lane]);
}

extern "C" void kernel_launch(void* const* d_in, const int* in_sizes, int n_in,
                              void* d_out, int out_size, void* d_ws, size_t ws_size,
                              hipStream_t stream) {
    const float* x      = (const float*)d_in[0];
    const float* efeats = (const float*)d_in[1];
    const int*   src    = (const int*)d_in[2];
    const int*   dst    = (const int*)d_in[3];
    const float* Wni    = (const float*)d_in[4];
    const float* Wfij   = (const float*)d_in[5];
    const float* Wnj    = (const float*)d_in[6];
    const float* Wsrc   = (const float*)d_in[7];
    const float* attn   = (const float*)d_in[8];
    const float* bias   = (const float*)d_in[9];

    float* out  = (float*)d_out;                      // [N, 256]
    float* fout = out + (size_t)N_NODES * HFO;        // [E, 64]

    float* ws     = (float*)d_ws;
    float* xni    = ws;                                   // N*64
    float* xnj    = xni + (size_t)N_NODES * 64;           // N*64
    float* hfeat  = xnj + (size_t)N_NODES * 64;           // N*256
    float* escore = hfeat + (size_t)N_NODES * 256;        // E*4 (e -> ex in place)
    float* denom  = escore + (size_t)N_EDGES * 4;         // N*4

    k0_init<<<2048, 256, 0, stream>>>(x, out, denom);
    k1_node_gemm<<<N_NODES / 8, 384, 0, stream>>>(x, Wni, Wnj, Wsrc, xni, xnj, hfeat);
    k2_edge<<<N_EDGES / 4, 256, 0, stream>>>(efeats, src, dst, Wfij, attn, bias,
                                             xni, xnj, fout, escore);
    k3_denom<<<(N_EDGES + 255) / 256, 256, 0, stream>>>(dst, escore, denom);
    k4_scatter<<<N_EDGES / 4, 256, 0, stream>>>(src, dst, escore, denom, hfeat, out);
}

// Round 2
// 455.896 us; speedup vs baseline: 1.3825x; 1.3825x over previous
//
#include <hip/hip_runtime.h>

#define N_NODES 20000
#define N_EDGES 320000
#define IN_F 256
#define EIN_F 64
#define NH 4
#define HFE 64   // H*FE
#define HFO 256  // H*FO

// ---------------- K1: fused node GEMM ----------------
// xni = x@W_ni [N,64], xnj = x@W_nj [N,64], hfeat = x@W_src [N,256]
// block = 384 threads (cols), 8 nodes per block, x rows staged in LDS.
__global__ __launch_bounds__(384) void k1_node_gemm(
    const float* __restrict__ x, const float* __restrict__ Wni,
    const float* __restrict__ Wnj, const float* __restrict__ Wsrc,
    float* __restrict__ xni, float* __restrict__ xnj, float* __restrict__ hfeat)
{
    __shared__ float xs[8][IN_F];
    const int n0 = blockIdx.x * 8;
    const int tid = threadIdx.x; // 0..383
    for (int i = tid; i < 8 * IN_F; i += 384) {
        int r = i >> 8, c = i & 255;
        xs[r][c] = x[(n0 + r) * IN_F + c];
    }
    __syncthreads();
    float acc[8];
#pragma unroll
    for (int i = 0; i < 8; i++) acc[i] = 0.f;

    const float* W;
    int ldw, col;
    if (tid < 64)       { W = Wni;  ldw = 64;  col = tid;       }
    else if (tid < 128) { W = Wnj;  ldw = 64;  col = tid - 64;  }
    else                { W = Wsrc; ldw = 256; col = tid - 128; }

    for (int k = 0; k < IN_F; k++) {
        float w = W[k * ldw + col];
#pragma unroll
        for (int i = 0; i < 8; i++) acc[i] += xs[i][k] * w;
    }

    if (tid < 64) {
#pragma unroll
        for (int i = 0; i < 8; i++) xni[(n0 + i) * 64 + col] = acc[i];
    } else if (tid < 128) {
#pragma unroll
        for (int i = 0; i < 8; i++) xnj[(n0 + i) * 64 + col] = acc[i];
    } else {
#pragma unroll
        for (int i = 0; i < 8; i++) hfeat[(n0 + i) * 256 + col] = acc[i];
    }
}

// ---------------- K2: per-edge scores ----------------
// f = leaky(efeats@W_fij + xni[src] + xnj[dst] + bias) -> fout; e = sum16(f*attn) -> escore
__global__ __launch_bounds__(256) void k2_edge(
    const float* __restrict__ efeats, const int* __restrict__ src, const int* __restrict__ dst,
    const float* __restrict__ Wfij, const float* __restrict__ attn, const float* __restrict__ bias,
    const float* __restrict__ xni, const float* __restrict__ xnj,
    float* __restrict__ fout, float* __restrict__ escore)
{
    __shared__ float Wf[64 * 64];
    __shared__ float efs[4][64];
    const int tid = threadIdx.x;
    for (int i = tid; i < 64 * 64; i += 256) Wf[i] = Wfij[i];

    const int w = tid >> 6, lane = tid & 63;
    const long e = (long)blockIdx.x * 4 + w;
    const bool valid = e < N_EDGES;
    if (valid) efs[w][lane] = efeats[e * 64 + lane];
    __syncthreads();
    if (!valid) return;

    float acc = 0.f;
#pragma unroll 8
    for (int k = 0; k < 64; k++) acc += efs[w][k] * Wf[k * 64 + lane];

    const int s = src[e], d = dst[e];
    float f = acc + xni[s * 64 + lane] + xnj[d * 64 + lane] + bias[lane];
    f = (f >= 0.f) ? f : 0.2f * f;
    fout[e * 64 + lane] = f;

    float p = f * attn[lane];           // attn flat [H*FE] matches lane layout
    p += __shfl_xor(p, 1, 64);
    p += __shfl_xor(p, 2, 64);
    p += __shfl_xor(p, 4, 64);
    p += __shfl_xor(p, 8, 64);
    if ((lane & 15) == 0) escore[e * 4 + (lane >> 4)] = p;
}

// ---------------- CSR build ----------------
__global__ void k_count(const int* __restrict__ dst, int* __restrict__ cnt) {
    int e = blockIdx.x * blockDim.x + threadIdx.x;
    if (e < N_EDGES) atomicAdd(&cnt[dst[e]], 1);
}

// single block, 1024 threads: exclusive scan of cnt[N] -> offs[N+1], copy to cur[N]
__global__ __launch_bounds__(1024) void k_scan(const int* __restrict__ cnt,
                                               int* __restrict__ offs, int* __restrict__ cur) {
    __shared__ int sums[1024];
    const int t = threadIdx.x;
    const int CH = (N_NODES + 1023) / 1024; // 20
    const int base = t * CH;
    int s = 0;
    for (int i = 0; i < CH; i++) {
        int idx = base + i;
        if (idx < N_NODES) s += cnt[idx];
    }
    sums[t] = s;
    __syncthreads();
    for (int off = 1; off < 1024; off <<= 1) {
        int v = (t >= off) ? sums[t - off] : 0;
        __syncthreads();
        sums[t] += v;
        __syncthreads();
    }
    int run = (t == 0) ? 0 : sums[t - 1];
    for (int i = 0; i < CH; i++) {
        int idx = base + i;
        if (idx < N_NODES) {
            offs[idx] = run;
            cur[idx] = run;
            run += cnt[idx];
        }
    }
    if (t == 1023) offs[N_NODES] = run;   // == E (chunks past N contribute 0)
}

__global__ void k_fill(const int* __restrict__ dst, int* __restrict__ cur,
                       int* __restrict__ eidx) {
    int e = blockIdx.x * blockDim.x + threadIdx.x;
    if (e >= N_EDGES) return;
    int pos = atomicAdd(&cur[dst[e]], 1);
    eidx[pos] = e;
}

// ---------------- K5: gather per dst node (wave per node) ----------------
// pass1: escore -> exp in place, accumulate denom; pass2: acc += (ex/denom)*hfeat[src]
__global__ __launch_bounds__(256) void k5_gather(
    const int* __restrict__ offs, const int* __restrict__ eidx,
    const int* __restrict__ src, float* __restrict__ escore,
    const float* __restrict__ hfeat, const float* __restrict__ x,
    float* __restrict__ out)
{
    const int w = threadIdx.x >> 6, lane = threadIdx.x & 63;
    const int d = blockIdx.x * 4 + w;
    if (d >= N_NODES) return;
    const int e0 = offs[d], e1 = offs[d + 1];
    const int deg = e1 - e0;

    const size_t ob = (size_t)d * 256;
    if (deg == 0) {
        out[ob + lane]       = x[ob + lane];
        out[ob + 64 + lane]  = x[ob + 64 + lane];
        out[ob + 128 + lane] = x[ob + 128 + lane];
        out[ob + 192 + lane] = x[ob + 192 + lane];
        return;
    }

    // pass 1: exp in place + denom
    float dn0 = 0.f, dn1 = 0.f, dn2 = 0.f, dn3 = 0.f;
    for (int base = 0; base < deg; base += 64) {
        if (base + lane < deg) {
            int eid = eidx[e0 + base + lane];
            float4 v = ((const float4*)escore)[eid];
            float4 ex;
            ex.x = __expf(v.x); ex.y = __expf(v.y);
            ex.z = __expf(v.z); ex.w = __expf(v.w);
            ((float4*)escore)[eid] = ex;
            dn0 += ex.x; dn1 += ex.y; dn2 += ex.z; dn3 += ex.w;
        }
    }
#pragma unroll
    for (int m = 1; m < 64; m <<= 1) {
        dn0 += __shfl_xor(dn0, m, 64);
        dn1 += __shfl_xor(dn1, m, 64);
        dn2 += __shfl_xor(dn2, m, 64);
        dn3 += __shfl_xor(dn3, m, 64);
    }
    const float i0 = 1.f / dn0, i1 = 1.f / dn1, i2 = 1.f / dn2, i3 = 1.f / dn3;

    // pass 2: serial over edges, lanes on feature dim
    float acc0 = 0.f, acc1 = 0.f, acc2 = 0.f, acc3 = 0.f;
    for (int i = 0; i < deg; i++) {
        const int eid = eidx[e0 + i];
        const float4 ex = ((const float4*)escore)[eid];
        const int s = src[eid];
        const float* hs = hfeat + (size_t)s * 256;
        acc0 += (ex.x * i0) * hs[lane];
        acc1 += (ex.y * i1) * hs[64 + lane];
        acc2 += (ex.z * i2) * hs[128 + lane];
        acc3 += (ex.w * i3) * hs[192 + lane];
    }

    out[ob + lane]       = x[ob + lane]       + acc0;
    out[ob + 64 + lane]  = x[ob + 64 + lane]  + acc1;
    out[ob + 128 + lane] = x[ob + 128 + lane] + acc2;
    out[ob + 192 + lane] = x[ob + 192 + lane] + acc3;
}

extern "C" void kernel_launch(void* const* d_in, const int* in_sizes, int n_in,
                              void* d_out, int out_size, void* d_ws, size_t ws_size,
                              hipStream_t stream) {
    const float* x      = (const float*)d_in[0];
    const float* efeats = (const float*)d_in[1];
    const int*   src    = (const int*)d_in[2];
    const int*   dst    = (const int*)d_in[3];
    const float* Wni    = (const float*)d_in[4];
    const float* Wfij   = (const float*)d_in[5];
    const float* Wnj    = (const float*)d_in[6];
    const float* Wsrc   = (const float*)d_in[7];
    const float* attn   = (const float*)d_in[8];
    const float* bias   = (const float*)d_in[9];

    float* out  = (float*)d_out;                      // [N, 256]
    float* fout = out + (size_t)N_NODES * HFO;        // [E, 64]

    float* ws     = (float*)d_ws;
    float* xni    = ws;                                   // N*64
    float* xnj    = xni + (size_t)N_NODES * 64;           // N*64
    float* hfeat  = xnj + (size_t)N_NODES * 64;           // N*256
    float* escore = hfeat + (size_t)N_NODES * 256;        // E*4 (raw e -> ex in place)
    int*   cnt    = (int*)(escore + (size_t)N_EDGES * 4); // N
    int*   offs   = cnt + N_NODES;                        // N+1
    int*   cur    = offs + N_NODES + 1;                   // N
    int*   eidx   = cur + N_NODES;                        // E

    hipMemsetAsync(cnt, 0, N_NODES * sizeof(int), stream);

    k1_node_gemm<<<N_NODES / 8, 384, 0, stream>>>(x, Wni, Wnj, Wsrc, xni, xnj, hfeat);
    k_count<<<(N_EDGES + 255) / 256, 256, 0, stream>>>(dst, cnt);
    k_scan<<<1, 1024, 0, stream>>>(cnt, offs, cur);
    k_fill<<<(N_EDGES + 255) / 256, 256, 0, stream>>>(dst, cur, eidx);
    k2_edge<<<N_EDGES / 4, 256, 0, stream>>>(efeats, src, dst, Wfij, attn, bias,
                                             xni, xnj, fout, escore);
    k5_gather<<<(N_NODES + 3) / 4, 256, 0, stream>>>(offs, eidx, src, escore, hfeat, x, out);
}

// Round 3
// 371.394 us; speedup vs baseline: 1.6970x; 1.2275x over previous
//
#include <hip/hip_runtime.h>

#define N_NODES 20000
#define N_EDGES 320000
#define IN_F 256
#define EIN_F 64
#define NH 4
#define HFE 64   // H*FE
#define HFO 256  // H*FO

typedef __attribute__((ext_vector_type(8))) short short8;   // 8 bf16 (4 VGPRs)
typedef __attribute__((ext_vector_type(4))) float f32x4;

__device__ inline short f2bf(float f) {
    unsigned u = __builtin_bit_cast(unsigned, f);
    unsigned r = (u + 0x7FFFu + ((u >> 16) & 1u)) >> 16;
    return (short)r;
}

// ---------------- K1: fused node GEMM ----------------
// xni = x@W_ni [N,64], xnj = x@W_nj [N,64], hfeat = x@W_src [N,256]
__global__ __launch_bounds__(384) void k1_node_gemm(
    const float* __restrict__ x, const float* __restrict__ Wni,
    const float* __restrict__ Wnj, const float* __restrict__ Wsrc,
    float* __restrict__ xni, float* __restrict__ xnj, float* __restrict__ hfeat)
{
    __shared__ float xs[8][IN_F];
    const int n0 = blockIdx.x * 8;
    const int tid = threadIdx.x; // 0..383
    for (int i = tid; i < 8 * IN_F; i += 384) {
        int r = i >> 8, c = i & 255;
        xs[r][c] = x[(n0 + r) * IN_F + c];
    }
    __syncthreads();
    float acc[8];
#pragma unroll
    for (int i = 0; i < 8; i++) acc[i] = 0.f;

    const float* W;
    int ldw, col;
    if (tid < 64)       { W = Wni;  ldw = 64;  col = tid;       }
    else if (tid < 128) { W = Wnj;  ldw = 64;  col = tid - 64;  }
    else                { W = Wsrc; ldw = 256; col = tid - 128; }

    for (int k = 0; k < IN_F; k++) {
        float w = W[k * ldw + col];
#pragma unroll
        for (int i = 0; i < 8; i++) acc[i] += xs[i][k] * w;
    }

    if (tid < 64) {
#pragma unroll
        for (int i = 0; i < 8; i++) xni[(n0 + i) * 64 + col] = acc[i];
    } else if (tid < 128) {
#pragma unroll
        for (int i = 0; i < 8; i++) xnj[(n0 + i) * 64 + col] = acc[i];
    } else {
#pragma unroll
        for (int i = 0; i < 8; i++) hfeat[(n0 + i) * 256 + col] = acc[i];
    }
}

// ---------------- K2: per-edge scores via MFMA ----------------
// Per wave, per iteration: 16 edges.
//   C[16e][64] = bf16(efeats[16e][64]) @ bf16(Wfij[64][64])   (8x mfma 16x16x32)
//   f = leaky(C + xni[src] + xnj[dst] + bias) -> fout;  e = sum16(f*attn) -> escore
__global__ __launch_bounds__(256) void k2_edge_mfma(
    const float* __restrict__ efeats, const int* __restrict__ src, const int* __restrict__ dst,
    const float* __restrict__ Wfij, const float* __restrict__ attn, const float* __restrict__ bias,
    const float* __restrict__ xni, const float* __restrict__ xnj,
    float* __restrict__ fout, float* __restrict__ escore)
{
    __shared__ float flds[4][16][68];       // per-wave private rotate buffer
    const int tid  = threadIdx.x;
    const int w    = tid >> 6;
    const int lane = tid & 63;
    const int l15  = lane & 15;
    const int g    = lane >> 4;             // 0..3

    const float bias_r = bias[lane];
    const float attn_r = attn[lane];

    // B-frags: Wfij[64][64] -> 8 frags in registers (once per wave)
    short8 bfr[2][4];
#pragma unroll
    for (int kb = 0; kb < 2; kb++) {
#pragma unroll
        for (int ct = 0; ct < 4; ct++) {
            const int col = ct * 16 + l15;
            const int k0  = kb * 32 + 8 * g;
            short8 v;
#pragma unroll
            for (int i = 0; i < 8; i++) v[i] = f2bf(Wfij[(k0 + i) * 64 + col]);
            bfr[kb][ct] = v;
        }
    }

    const int nwaves = gridDim.x * 4;
    const int gwid = blockIdx.x * 4 + w;
    const int ngroups = N_EDGES / 16;       // 20000

    for (int grp = gwid; grp < ngroups; grp += nwaves) {
        const int e0 = grp * 16;

        f32x4 c[4];
#pragma unroll
        for (int ct = 0; ct < 4; ct++) c[ct] = (f32x4){0.f, 0.f, 0.f, 0.f};

#pragma unroll
        for (int kb = 0; kb < 2; kb++) {
            const float* ap = efeats + (size_t)(e0 + l15) * 64 + kb * 32 + 8 * g;
            float4 a0 = *(const float4*)ap;
            float4 a1 = *(const float4*)(ap + 4);
            short8 afr;
            afr[0] = f2bf(a0.x); afr[1] = f2bf(a0.y); afr[2] = f2bf(a0.z); afr[3] = f2bf(a0.w);
            afr[4] = f2bf(a1.x); afr[5] = f2bf(a1.y); afr[6] = f2bf(a1.z); afr[7] = f2bf(a1.w);
#pragma unroll
            for (int ct = 0; ct < 4; ct++)
                c[ct] = __builtin_amdgcn_mfma_f32_16x16x32_bf16(afr, bfr[kb][ct], c[ct], 0, 0, 0);
        }

        // rotate C (col=lane&15, row=4*g+reg) -> lane=col layout via per-wave LDS
#pragma unroll
        for (int ct = 0; ct < 4; ct++) {
#pragma unroll
            for (int reg = 0; reg < 4; reg++)
                flds[w][4 * g + reg][ct * 16 + l15] = c[ct][reg];
        }

        // epilogue: one edge at a time, lanes = 64 cols
        for (int i = 0; i < 16; i++) {
            const int e = e0 + i;
            const int s = src[e], d = dst[e];
            float f = flds[w][i][lane] + xni[s * 64 + lane] + xnj[d * 64 + lane] + bias_r;
            f = (f >= 0.f) ? f : 0.2f * f;
            fout[(size_t)e * 64 + lane] = f;

            float p = f * attn_r;
            p += __shfl_xor(p, 1, 64);
            p += __shfl_xor(p, 2, 64);
            p += __shfl_xor(p, 4, 64);
            p += __shfl_xor(p, 8, 64);
            if (l15 == 0) escore[e * 4 + g] = p;
        }
    }
}

// ---------------- CSR build ----------------
__global__ void k_count(const int* __restrict__ dst, int* __restrict__ cnt) {
    int e = blockIdx.x * blockDim.x + threadIdx.x;
    if (e < N_EDGES) atomicAdd(&cnt[dst[e]], 1);
}

__global__ __launch_bounds__(1024) void k_scan(const int* __restrict__ cnt,
                                               int* __restrict__ offs, int* __restrict__ cur) {
    __shared__ int sums[1024];
    const int t = threadIdx.x;
    const int CH = (N_NODES + 1023) / 1024; // 20
    const int base = t * CH;
    int s = 0;
    for (int i = 0; i < CH; i++) {
        int idx = base + i;
        if (idx < N_NODES) s += cnt[idx];
    }
    sums[t] = s;
    __syncthreads();
    for (int off = 1; off < 1024; off <<= 1) {
        int v = (t >= off) ? sums[t - off] : 0;
        __syncthreads();
        sums[t] += v;
        __syncthreads();
    }
    int run = (t == 0) ? 0 : sums[t - 1];
    for (int i = 0; i < CH; i++) {
        int idx = base + i;
        if (idx < N_NODES) {
            offs[idx] = run;
            cur[idx] = run;
            run += cnt[idx];
        }
    }
    if (t == 1023) offs[N_NODES] = run;
}

__global__ void k_fill(const int* __restrict__ dst, int* __restrict__ cur,
                       int* __restrict__ eidx) {
    int e = blockIdx.x * blockDim.x + threadIdx.x;
    if (e >= N_EDGES) return;
    int pos = atomicAdd(&cur[dst[e]], 1);
    eidx[pos] = e;
}

// ---------------- K5: gather per dst node (wave per node) ----------------
__global__ __launch_bounds__(256) void k5_gather(
    const int* __restrict__ offs, const int* __restrict__ eidx,
    const int* __restrict__ src, float* __restrict__ escore,
    const float* __restrict__ hfeat, const float* __restrict__ x,
    float* __restrict__ out)
{
    const int w = threadIdx.x >> 6, lane = threadIdx.x & 63;
    const int d = blockIdx.x * 4 + w;
    if (d >= N_NODES) return;
    const int e0 = offs[d], e1 = offs[d + 1];
    const int deg = e1 - e0;

    const size_t ob = (size_t)d * 256;
    if (deg == 0) {
        out[ob + lane]       = x[ob + lane];
        out[ob + 64 + lane]  = x[ob + 64 + lane];
        out[ob + 128 + lane] = x[ob + 128 + lane];
        out[ob + 192 + lane] = x[ob + 192 + lane];
        return;
    }

    float dn0 = 0.f, dn1 = 0.f, dn2 = 0.f, dn3 = 0.f;
    for (int base = 0; base < deg; base += 64) {
        if (base + lane < deg) {
            int eid = eidx[e0 + base + lane];
            float4 v = ((const float4*)escore)[eid];
            float4 ex;
            ex.x = __expf(v.x); ex.y = __expf(v.y);
            ex.z = __expf(v.z); ex.w = __expf(v.w);
            ((float4*)escore)[eid] = ex;
            dn0 += ex.x; dn1 += ex.y; dn2 += ex.z; dn3 += ex.w;
        }
    }
#pragma unroll
    for (int m = 1; m < 64; m <<= 1) {
        dn0 += __shfl_xor(dn0, m, 64);
        dn1 += __shfl_xor(dn1, m, 64);
        dn2 += __shfl_xor(dn2, m, 64);
        dn3 += __shfl_xor(dn3, m, 64);
    }
    const float i0 = 1.f / dn0, i1 = 1.f / dn1, i2 = 1.f / dn2, i3 = 1.f / dn3;

    float acc0 = 0.f, acc1 = 0.f, acc2 = 0.f, acc3 = 0.f;
    for (int i = 0; i < deg; i++) {
        const int eid = eidx[e0 + i];
        const float4 ex = ((const float4*)escore)[eid];
        const int s = src[eid];
        const float* hs = hfeat + (size_t)s * 256;
        acc0 += (ex.x * i0) * hs[lane];
        acc1 += (ex.y * i1) * hs[64 + lane];
        acc2 += (ex.z * i2) * hs[128 + lane];
        acc3 += (ex.w * i3) * hs[192 + lane];
    }

    out[ob + lane]       = x[ob + lane]       + acc0;
    out[ob + 64 + lane]  = x[ob + 64 + lane]  + acc1;
    out[ob + 128 + lane] = x[ob + 128 + lane] + acc2;
    out[ob + 192 + lane] = x[ob + 192 + lane] + acc3;
}

extern "C" void kernel_launch(void* const* d_in, const int* in_sizes, int n_in,
                              void* d_out, int out_size, void* d_ws, size_t ws_size,
                              hipStream_t stream) {
    const float* x      = (const float*)d_in[0];
    const float* efeats = (const float*)d_in[1];
    const int*   src    = (const int*)d_in[2];
    const int*   dst    = (const int*)d_in[3];
    const float* Wni    = (const float*)d_in[4];
    const float* Wfij   = (const float*)d_in[5];
    const float* Wnj    = (const float*)d_in[6];
    const float* Wsrc   = (const float*)d_in[7];
    const float* attn   = (const float*)d_in[8];
    const float* bias   = (const float*)d_in[9];

    float* out  = (float*)d_out;                      // [N, 256]
    float* fout = out + (size_t)N_NODES * HFO;        // [E, 64]

    float* ws     = (float*)d_ws;
    float* xni    = ws;                                   // N*64
    float* xnj    = xni + (size_t)N_NODES * 64;           // N*64
    float* hfeat  = xnj + (size_t)N_NODES * 64;           // N*256
    float* escore = hfeat + (size_t)N_NODES * 256;        // E*4 (raw e -> ex in place)
    int*   cnt    = (int*)(escore + (size_t)N_EDGES * 4); // N
    int*   offs   = cnt + N_NODES;                        // N+1
    int*   cur    = offs + N_NODES + 1;                   // N
    int*   eidx   = cur + N_NODES;                        // E

    hipMemsetAsync(cnt, 0, N_NODES * sizeof(int), stream);

    k1_node_gemm<<<N_NODES / 8, 384, 0, stream>>>(x, Wni, Wnj, Wsrc, xni, xnj, hfeat);
    k_count<<<(N_EDGES + 255) / 256, 256, 0, stream>>>(dst, cnt);
    k_scan<<<1, 1024, 0, stream>>>(cnt, offs, cur);
    k_fill<<<(N_EDGES + 255) / 256, 256, 0, stream>>>(dst, cur, eidx);
    k2_edge_mfma<<<640, 256, 0, stream>>>(efeats, src, dst, Wfij, attn, bias,
                                          xni, xnj, fout, escore);
    k5_gather<<<(N_NODES + 3) / 4, 256, 0, stream>>>(offs, eidx, src, escore, hfeat, x, out);
}

// Round 4
// 314.229 us; speedup vs baseline: 2.0057x; 1.1819x over previous
//
#include <hip/hip_runtime.h>

#define N_NODES 20000
#define N_EDGES 320000
#define IN_F 256
#define EIN_F 64
#define NH 4
#define HFE 64   // H*FE
#define HFO 256  // H*FO
#define NCOL 384 // 64+64+256 fused output cols

typedef __attribute__((ext_vector_type(8))) short short8;   // 8 bf16 (4 VGPRs)
typedef __attribute__((ext_vector_type(4))) float f32x4;

__device__ inline short f2bf(float f) {
    unsigned u = __builtin_bit_cast(unsigned, f);
    unsigned r = (u + 0x7FFFu + ((u >> 16) & 1u)) >> 16;
    return (short)r;
}

// ---------------- K0: pack [Wni|Wnj|Wsrc] -> bf16 fragment order ----------------
// wpack frag layout: [kb (8)][ct (24)][lane (64)][i (8)]
//   lane = ((k>>3)&3)*16 + (col&15),  i = k&7,  kb = k>>5, ct = col>>4
__global__ void k_pack_w(const float* __restrict__ Wni, const float* __restrict__ Wnj,
                         const float* __restrict__ Wsrc, short* __restrict__ wpack) {
    int idx = blockIdx.x * 256 + threadIdx.x;   // k*384 + col
    if (idx >= IN_F * NCOL) return;
    int k = idx / NCOL, col = idx % NCOL;
    float v;
    if (col < 64)        v = Wni[k * 64 + col];
    else if (col < 128)  v = Wnj[k * 64 + (col - 64)];
    else                 v = Wsrc[k * 256 + (col - 128)];
    int kb = k >> 5, ct = col >> 4, g = (k >> 3) & 3, i = k & 7, l15 = col & 15;
    int lane = g * 16 + l15;
    wpack[(((kb * 24 + ct) * 64) + lane) * 8 + i] = f2bf(v);
}

// ---------------- K1: fused node GEMM via MFMA ----------------
// [20000,256] @ [256,384] -> xni(0:64) | xnj(64:128) | hfeat(128:384)
// block = 4 waves x 16 rows = 64 rows; B-frags streamed from L2 (wpack).
__global__ __launch_bounds__(256) void k1_mfma(
    const float* __restrict__ x, const short* __restrict__ wpack,
    float* __restrict__ xni, float* __restrict__ xnj, float* __restrict__ hfeat)
{
    const int tid  = threadIdx.x;
    const int w    = tid >> 6;
    const int lane = tid & 63;
    const int l15  = lane & 15;
    const int g    = lane >> 4;

    const int r0 = blockIdx.x * 64 + w * 16;
    const int rload = min(r0 + l15, N_NODES - 1);   // clamp tail reads

    f32x4 acc[24];
#pragma unroll
    for (int ct = 0; ct < 24; ct++) acc[ct] = (f32x4){0.f, 0.f, 0.f, 0.f};

    const short8* bp = (const short8*)wpack;

    for (int kb = 0; kb < 8; kb++) {
        const float* ap = x + (size_t)rload * 256 + kb * 32 + 8 * g;
        float4 a0 = *(const float4*)ap;
        float4 a1 = *(const float4*)(ap + 4);
        short8 afr;
        afr[0] = f2bf(a0.x); afr[1] = f2bf(a0.y); afr[2] = f2bf(a0.z); afr[3] = f2bf(a0.w);
        afr[4] = f2bf(a1.x); afr[5] = f2bf(a1.y); afr[6] = f2bf(a1.z); afr[7] = f2bf(a1.w);
        const short8* bkb = bp + (size_t)kb * 24 * 64 + lane;
#pragma unroll
        for (int ct = 0; ct < 24; ct++)
            acc[ct] = __builtin_amdgcn_mfma_f32_16x16x32_bf16(afr, bkb[ct * 64], acc[ct], 0, 0, 0);
    }

    // C layout (validated in k2): row = 4*g + reg, col = ct*16 + l15
    const int rowb = r0 + 4 * g;
    if (rowb >= N_NODES) return;
#pragma unroll
    for (int ct = 0; ct < 24; ct++) {
        const int col = ct * 16 + l15;
#pragma unroll
        for (int reg = 0; reg < 4; reg++) {
            const int row = rowb + reg;
            if (row < N_NODES) {
                if (col < 64)        xni[(size_t)row * 64 + col] = acc[ct][reg];
                else if (col < 128)  xnj[(size_t)row * 64 + (col - 64)] = acc[ct][reg];
                else                 hfeat[(size_t)row * 256 + (col - 128)] = acc[ct][reg];
            }
        }
    }
}

// ---------------- K2: per-edge scores via MFMA ----------------
__global__ __launch_bounds__(256) void k2_edge_mfma(
    const float* __restrict__ efeats, const int* __restrict__ src, const int* __restrict__ dst,
    const float* __restrict__ Wfij, const float* __restrict__ attn, const float* __restrict__ bias,
    const float* __restrict__ xni, const float* __restrict__ xnj,
    float* __restrict__ fout, float* __restrict__ escore)
{
    __shared__ float flds[4][16][68];       // per-wave private rotate buffer
    const int tid  = threadIdx.x;
    const int w    = tid >> 6;
    const int lane = tid & 63;
    const int l15  = lane & 15;
    const int g    = lane >> 4;             // 0..3

    const float bias_r = bias[lane];
    const float attn_r = attn[lane];

    // B-frags: Wfij[64][64] -> 8 frags in registers (once per wave)
    short8 bfr[2][4];
#pragma unroll
    for (int kb = 0; kb < 2; kb++) {
#pragma unroll
        for (int ct = 0; ct < 4; ct++) {
            const int col = ct * 16 + l15;
            const int k0  = kb * 32 + 8 * g;
            short8 v;
#pragma unroll
            for (int i = 0; i < 8; i++) v[i] = f2bf(Wfij[(k0 + i) * 64 + col]);
            bfr[kb][ct] = v;
        }
    }

    const int nwaves = gridDim.x * 4;
    const int gwid = blockIdx.x * 4 + w;
    const int ngroups = N_EDGES / 16;       // 20000

    for (int grp = gwid; grp < ngroups; grp += nwaves) {
        const int e0 = grp * 16;

        f32x4 c[4];
#pragma unroll
        for (int ct = 0; ct < 4; ct++) c[ct] = (f32x4){0.f, 0.f, 0.f, 0.f};

#pragma unroll
        for (int kb = 0; kb < 2; kb++) {
            const float* ap = efeats + (size_t)(e0 + l15) * 64 + kb * 32 + 8 * g;
            float4 a0 = *(const float4*)ap;
            float4 a1 = *(const float4*)(ap + 4);
            short8 afr;
            afr[0] = f2bf(a0.x); afr[1] = f2bf(a0.y); afr[2] = f2bf(a0.z); afr[3] = f2bf(a0.w);
            afr[4] = f2bf(a1.x); afr[5] = f2bf(a1.y); afr[6] = f2bf(a1.z); afr[7] = f2bf(a1.w);
#pragma unroll
            for (int ct = 0; ct < 4; ct++)
                c[ct] = __builtin_amdgcn_mfma_f32_16x16x32_bf16(afr, bfr[kb][ct], c[ct], 0, 0, 0);
        }

        // rotate C (col=lane&15, row=4*g+reg) -> lane=col layout via per-wave LDS
#pragma unroll
        for (int ct = 0; ct < 4; ct++) {
#pragma unroll
            for (int reg = 0; reg < 4; reg++)
                flds[w][4 * g + reg][ct * 16 + l15] = c[ct][reg];
        }

        // epilogue: one edge at a time, lanes = 64 cols
        for (int i = 0; i < 16; i++) {
            const int e = e0 + i;
            const int s = src[e], d = dst[e];
            float f = flds[w][i][lane] + xni[s * 64 + lane] + xnj[d * 64 + lane] + bias_r;
            f = (f >= 0.f) ? f : 0.2f * f;
            fout[(size_t)e * 64 + lane] = f;

            float p = f * attn_r;
            p += __shfl_xor(p, 1, 64);
            p += __shfl_xor(p, 2, 64);
            p += __shfl_xor(p, 4, 64);
            p += __shfl_xor(p, 8, 64);
            if (l15 == 0) escore[e * 4 + g] = p;
        }
    }
}

// ---------------- CSR build ----------------
__global__ void k_count(const int* __restrict__ dst, int* __restrict__ cnt) {
    int e = blockIdx.x * blockDim.x + threadIdx.x;
    if (e < N_EDGES) atomicAdd(&cnt[dst[e]], 1);
}

__global__ __launch_bounds__(1024) void k_scan(const int* __restrict__ cnt,
                                               int* __restrict__ offs, int* __restrict__ cur) {
    __shared__ int sums[1024];
    const int t = threadIdx.x;
    const int CH = (N_NODES + 1023) / 1024; // 20
    const int base = t * CH;
    int s = 0;
    for (int i = 0; i < CH; i++) {
        int idx = base + i;
        if (idx < N_NODES) s += cnt[idx];
    }
    sums[t] = s;
    __syncthreads();
    for (int off = 1; off < 1024; off <<= 1) {
        int v = (t >= off) ? sums[t - off] : 0;
        __syncthreads();
        sums[t] += v;
        __syncthreads();
    }
    int run = (t == 0) ? 0 : sums[t - 1];
    for (int i = 0; i < CH; i++) {
        int idx = base + i;
        if (idx < N_NODES) {
            offs[idx] = run;
            cur[idx] = run;
            run += cnt[idx];
        }
    }
    if (t == 1023) offs[N_NODES] = run;
}

__global__ void k_fill(const int* __restrict__ dst, int* __restrict__ cur,
                       int* __restrict__ eidx) {
    int e = blockIdx.x * blockDim.x + threadIdx.x;
    if (e >= N_EDGES) return;
    int pos = atomicAdd(&cur[dst[e]], 1);
    eidx[pos] = e;
}

// ---------------- K5: gather per dst node (wave per node) ----------------
__global__ __launch_bounds__(256) void k5_gather(
    const int* __restrict__ offs, const int* __restrict__ eidx,
    const int* __restrict__ src, float* __restrict__ escore,
    const float* __restrict__ hfeat, const float* __restrict__ x,
    float* __restrict__ out)
{
    const int w = threadIdx.x >> 6, lane = threadIdx.x & 63;
    const int d = blockIdx.x * 4 + w;
    if (d >= N_NODES) return;
    const int e0 = offs[d], e1 = offs[d + 1];
    const int deg = e1 - e0;

    const size_t ob = (size_t)d * 256;
    if (deg == 0) {
        out[ob + lane]       = x[ob + lane];
        out[ob + 64 + lane]  = x[ob + 64 + lane];
        out[ob + 128 + lane] = x[ob + 128 + lane];
        out[ob + 192 + lane] = x[ob + 192 + lane];
        return;
    }

    float dn0 = 0.f, dn1 = 0.f, dn2 = 0.f, dn3 = 0.f;
    for (int base = 0; base < deg; base += 64) {
        if (base + lane < deg) {
            int eid = eidx[e0 + base + lane];
            float4 v = ((const float4*)escore)[eid];
            float4 ex;
            ex.x = __expf(v.x); ex.y = __expf(v.y);
            ex.z = __expf(v.z); ex.w = __expf(v.w);
            ((float4*)escore)[eid] = ex;
            dn0 += ex.x; dn1 += ex.y; dn2 += ex.z; dn3 += ex.w;
        }
    }
#pragma unroll
    for (int m = 1; m < 64; m <<= 1) {
        dn0 += __shfl_xor(dn0, m, 64);
        dn1 += __shfl_xor(dn1, m, 64);
        dn2 += __shfl_xor(dn2, m, 64);
        dn3 += __shfl_xor(dn3, m, 64);
    }
    const float i0 = 1.f / dn0, i1 = 1.f / dn1, i2 = 1.f / dn2, i3 = 1.f / dn3;

    float acc0 = 0.f, acc1 = 0.f, acc2 = 0.f, acc3 = 0.f;
    for (int i = 0; i < deg; i++) {
        const int eid = eidx[e0 + i];
        const float4 ex = ((const float4*)escore)[eid];
        const int s = src[eid];
        const float* hs = hfeat + (size_t)s * 256;
        acc0 += (ex.x * i0) * hs[lane];
        acc1 += (ex.y * i1) * hs[64 + lane];
        acc2 += (ex.z * i2) * hs[128 + lane];
        acc3 += (ex.w * i3) * hs[192 + lane];
    }

    out[ob + lane]       = x[ob + lane]       + acc0;
    out[ob + 64 + lane]  = x[ob + 64 + lane]  + acc1;
    out[ob + 128 + lane] = x[ob + 128 + lane] + acc2;
    out[ob + 192 + lane] = x[ob + 192 + lane] + acc3;
}

extern "C" void kernel_launch(void* const* d_in, const int* in_sizes, int n_in,
                              void* d_out, int out_size, void* d_ws, size_t ws_size,
                              hipStream_t stream) {
    const float* x      = (const float*)d_in[0];
    const float* efeats = (const float*)d_in[1];
    const int*   src    = (const int*)d_in[2];
    const int*   dst    = (const int*)d_in[3];
    const float* Wni    = (const float*)d_in[4];
    const float* Wfij   = (const float*)d_in[5];
    const float* Wnj    = (const float*)d_in[6];
    const float* Wsrc   = (const float*)d_in[7];
    const float* attn   = (const float*)d_in[8];
    const float* bias   = (const float*)d_in[9];

    float* out  = (float*)d_out;                      // [N, 256]
    float* fout = out + (size_t)N_NODES * HFO;        // [E, 64]

    float* ws     = (float*)d_ws;
    float* xni    = ws;                                   // N*64
    float* xnj    = xni + (size_t)N_NODES * 64;           // N*64
    float* hfeat  = xnj + (size_t)N_NODES * 64;           // N*256
    float* escore = hfeat + (size_t)N_NODES * 256;        // E*4 (raw e -> ex in place)
    int*   cnt    = (int*)(escore + (size_t)N_EDGES * 4); // N
    int*   offs   = cnt + N_NODES;                        // N+1
    int*   cur    = offs + N_NODES + 1;                   // N
    int*   eidx   = cur + N_NODES;                        // E
    short* wpack  = (short*)(eidx + N_EDGES);             // 256*384 bf16

    hipMemsetAsync(cnt, 0, N_NODES * sizeof(int), stream);

    k_pack_w<<<(IN_F * NCOL + 255) / 256, 256, 0, stream>>>(Wni, Wnj, Wsrc, wpack);
    k1_mfma<<<(N_NODES + 63) / 64, 256, 0, stream>>>(x, wpack, xni, xnj, hfeat);
    k_count<<<(N_EDGES + 255) / 256, 256, 0, stream>>>(dst, cnt);
    k_scan<<<1, 1024, 0, stream>>>(cnt, offs, cur);
    k_fill<<<(N_EDGES + 255) / 256, 256, 0, stream>>>(dst, cur, eidx);
    k2_edge_mfma<<<640, 256, 0, stream>>>(efeats, src, dst, Wfij, attn, bias,
                                          xni, xnj, fout, escore);
    k5_gather<<<(N_NODES + 3) / 4, 256, 0, stream>>>(offs, eidx, src, escore, hfeat, x, out);
}

// Round 5
// 281.024 us; speedup vs baseline: 2.2427x; 1.1182x over previous
//
#include <hip/hip_runtime.h>

#define N_NODES 20000
#define N_EDGES 320000
#define IN_F 256
#define EIN_F 64
#define NH 4
#define HFE 64   // H*FE
#define HFO 256  // H*FO
#define NCOL 384 // 64+64+256 fused output cols

typedef __attribute__((ext_vector_type(8))) short short8;   // 8 bf16 (4 VGPRs)
typedef __attribute__((ext_vector_type(4))) float f32x4;

__device__ inline short f2bf(float f) {
    unsigned u = __builtin_bit_cast(unsigned, f);
    unsigned r = (u + 0x7FFFu + ((u >> 16) & 1u)) >> 16;
    return (short)r;
}

// ---------------- K0: pack [Wni|Wnj|Wsrc] -> bf16 fragment order ----------------
__global__ void k_pack_w(const float* __restrict__ Wni, const float* __restrict__ Wnj,
                         const float* __restrict__ Wsrc, short* __restrict__ wpack) {
    int idx = blockIdx.x * 256 + threadIdx.x;   // k*384 + col
    if (idx >= IN_F * NCOL) return;
    int k = idx / NCOL, col = idx % NCOL;
    float v;
    if (col < 64)        v = Wni[k * 64 + col];
    else if (col < 128)  v = Wnj[k * 64 + (col - 64)];
    else                 v = Wsrc[k * 256 + (col - 128)];
    int kb = k >> 5, ct = col >> 4, g = (k >> 3) & 3, i = k & 7, l15 = col & 15;
    int lane = g * 16 + l15;
    wpack[(((kb * 24 + ct) * 64) + lane) * 8 + i] = f2bf(v);
}

// ---------------- K1: fused node GEMM via MFMA ----------------
__global__ __launch_bounds__(256) void k1_mfma(
    const float* __restrict__ x, const short* __restrict__ wpack,
    float* __restrict__ xni, float* __restrict__ xnj, float* __restrict__ hfeat)
{
    const int tid  = threadIdx.x;
    const int w    = tid >> 6;
    const int lane = tid & 63;
    const int l15  = lane & 15;
    const int g    = lane >> 4;

    const int r0 = blockIdx.x * 64 + w * 16;
    const int rload = min(r0 + l15, N_NODES - 1);   // clamp tail reads

    f32x4 acc[24];
#pragma unroll
    for (int ct = 0; ct < 24; ct++) acc[ct] = (f32x4){0.f, 0.f, 0.f, 0.f};

    const short8* bp = (const short8*)wpack;

    for (int kb = 0; kb < 8; kb++) {
        const float* ap = x + (size_t)rload * 256 + kb * 32 + 8 * g;
        float4 a0 = *(const float4*)ap;
        float4 a1 = *(const float4*)(ap + 4);
        short8 afr;
        afr[0] = f2bf(a0.x); afr[1] = f2bf(a0.y); afr[2] = f2bf(a0.z); afr[3] = f2bf(a0.w);
        afr[4] = f2bf(a1.x); afr[5] = f2bf(a1.y); afr[6] = f2bf(a1.z); afr[7] = f2bf(a1.w);
        const short8* bkb = bp + (size_t)kb * 24 * 64 + lane;
#pragma unroll
        for (int ct = 0; ct < 24; ct++)
            acc[ct] = __builtin_amdgcn_mfma_f32_16x16x32_bf16(afr, bkb[ct * 64], acc[ct], 0, 0, 0);
    }

    const int rowb = r0 + 4 * g;
    if (rowb >= N_NODES) return;
#pragma unroll
    for (int ct = 0; ct < 24; ct++) {
        const int col = ct * 16 + l15;
#pragma unroll
        for (int reg = 0; reg < 4; reg++) {
            const int row = rowb + reg;
            if (row < N_NODES) {
                if (col < 64)        xni[(size_t)row * 64 + col] = acc[ct][reg];
                else if (col < 128)  xnj[(size_t)row * 64 + (col - 64)] = acc[ct][reg];
                else                 hfeat[(size_t)row * 256 + (col - 128)] = acc[ct][reg];
            }
        }
    }
}

// ---------------- K2: per-edge scores via MFMA, LDS-free C-layout epilogue ----------------
// escore <- exp(e) directly; denom accumulated atomically here (k5 pass1 removed).
__global__ __launch_bounds__(256) void k2_edge_mfma(
    const float* __restrict__ efeats, const int* __restrict__ src, const int* __restrict__ dst,
    const float* __restrict__ Wfij, const float* __restrict__ attn, const float* __restrict__ bias,
    const float* __restrict__ xni, const float* __restrict__ xnj,
    float* __restrict__ fout, float* __restrict__ escore, float* __restrict__ denom)
{
    const int tid  = threadIdx.x;
    const int w    = tid >> 6;
    const int lane = tid & 63;
    const int l15  = lane & 15;
    const int g    = lane >> 4;             // 0..3

    // per-lane constants in C layout: col = ct*16 + l15
    float bias_c[4], attn_c[4];
#pragma unroll
    for (int ct = 0; ct < 4; ct++) {
        bias_c[ct] = bias[ct * 16 + l15];
        attn_c[ct] = attn[ct * 16 + l15];
    }

    // B-frags: Wfij[64][64] -> 8 frags in registers (once per wave)
    short8 bfr[2][4];
#pragma unroll
    for (int kb = 0; kb < 2; kb++) {
#pragma unroll
        for (int ct = 0; ct < 4; ct++) {
            const int col = ct * 16 + l15;
            const int k0  = kb * 32 + 8 * g;
            short8 v;
#pragma unroll
            for (int i = 0; i < 8; i++) v[i] = f2bf(Wfij[(k0 + i) * 64 + col]);
            bfr[kb][ct] = v;
        }
    }

    const int nwaves = gridDim.x * 4;
    const int gwid = blockIdx.x * 4 + w;
    const int ngroups = N_EDGES / 16;       // 20000

    for (int grp = gwid; grp < ngroups; grp += nwaves) {
        const int e0 = grp * 16;

        // prefetch edge indices (lanes 0..15 hold them; replicated across g)
        const int sv = src[e0 + l15];
        const int dv = dst[e0 + l15];

        f32x4 c[4];
#pragma unroll
        for (int ct = 0; ct < 4; ct++) c[ct] = (f32x4){0.f, 0.f, 0.f, 0.f};

#pragma unroll
        for (int kb = 0; kb < 2; kb++) {
            const float* ap = efeats + (size_t)(e0 + l15) * 64 + kb * 32 + 8 * g;
            float4 a0 = *(const float4*)ap;
            float4 a1 = *(const float4*)(ap + 4);
            short8 afr;
            afr[0] = f2bf(a0.x); afr[1] = f2bf(a0.y); afr[2] = f2bf(a0.z); afr[3] = f2bf(a0.w);
            afr[4] = f2bf(a1.x); afr[5] = f2bf(a1.y); afr[6] = f2bf(a1.z); afr[7] = f2bf(a1.w);
#pragma unroll
            for (int ct = 0; ct < 4; ct++)
                c[ct] = __builtin_amdgcn_mfma_f32_16x16x32_bf16(afr, bfr[kb][ct], c[ct], 0, 0, 0);
        }

        // epilogue in C layout: element (ct,reg) of lane (g,l15) is
        // edge e = e0 + 4*g + reg, col = ct*16 + l15
#pragma unroll
        for (int reg = 0; reg < 4; reg++) {
            const int eoff = 4 * g + reg;
            const int e = e0 + eoff;
            const int s = __shfl(sv, eoff, 64);
            const int d = __shfl(dv, eoff, 64);

            float f[4], p[4];
#pragma unroll
            for (int ct = 0; ct < 4; ct++) {
                float v = c[ct][reg] + xni[(size_t)s * 64 + ct * 16 + l15]
                                     + xnj[(size_t)d * 64 + ct * 16 + l15] + bias_c[ct];
                v = (v >= 0.f) ? v : 0.2f * v;
                f[ct] = v;
                p[ct] = v * attn_c[ct];
            }
#pragma unroll
            for (int ct = 0; ct < 4; ct++)
                fout[(size_t)e * 64 + ct * 16 + l15] = f[ct];
#pragma unroll
            for (int ct = 0; ct < 4; ct++) {
                p[ct] += __shfl_xor(p[ct], 1, 64);
                p[ct] += __shfl_xor(p[ct], 2, 64);
                p[ct] += __shfl_xor(p[ct], 4, 64);
                p[ct] += __shfl_xor(p[ct], 8, 64);
            }
            if (l15 == 0) {
#pragma unroll
                for (int ct = 0; ct < 4; ct++) {
                    float exv = __expf(p[ct]);
                    escore[(size_t)e * 4 + ct] = exv;
                    atomicAdd(&denom[(size_t)d * 4 + ct], exv);
                }
            }
        }
    }
}

// ---------------- CSR build ----------------
__global__ void k_count(const int* __restrict__ dst, int* __restrict__ cnt) {
    int e = blockIdx.x * blockDim.x + threadIdx.x;
    if (e < N_EDGES) atomicAdd(&cnt[dst[e]], 1);
}

__global__ __launch_bounds__(1024) void k_scan(const int* __restrict__ cnt,
                                               int* __restrict__ offs, int* __restrict__ cur) {
    __shared__ int sums[1024];
    const int t = threadIdx.x;
    const int CH = (N_NODES + 1023) / 1024; // 20
    const int base = t * CH;
    int s = 0;
    for (int i = 0; i < CH; i++) {
        int idx = base + i;
        if (idx < N_NODES) s += cnt[idx];
    }
    sums[t] = s;
    __syncthreads();
    for (int off = 1; off < 1024; off <<= 1) {
        int v = (t >= off) ? sums[t - off] : 0;
        __syncthreads();
        sums[t] += v;
        __syncthreads();
    }
    int run = (t == 0) ? 0 : sums[t - 1];
    for (int i = 0; i < CH; i++) {
        int idx = base + i;
        if (idx < N_NODES) {
            offs[idx] = run;
            cur[idx] = run;
            run += cnt[idx];
        }
    }
    if (t == 1023) offs[N_NODES] = run;
}

__global__ void k_fill(const int* __restrict__ dst, int* __restrict__ cur,
                       int* __restrict__ eidx) {
    int e = blockIdx.x * blockDim.x + threadIdx.x;
    if (e >= N_EDGES) return;
    int pos = atomicAdd(&cur[dst[e]], 1);
    eidx[pos] = e;
}

// ---------------- K5: gather per dst node (wave per node), single pass ----------------
__global__ __launch_bounds__(256) void k5_gather(
    const int* __restrict__ offs, const int* __restrict__ eidx,
    const int* __restrict__ src, const float* __restrict__ escore,
    const float* __restrict__ denom, const float* __restrict__ hfeat,
    const float* __restrict__ x, float* __restrict__ out)
{
    const int w = threadIdx.x >> 6, lane = threadIdx.x & 63;
    const int d = blockIdx.x * 4 + w;
    if (d >= N_NODES) return;
    const int e0 = offs[d], e1 = offs[d + 1];
    const int deg = e1 - e0;

    const size_t ob = (size_t)d * 256;
    if (deg == 0) {
        out[ob + lane]       = x[ob + lane];
        out[ob + 64 + lane]  = x[ob + 64 + lane];
        out[ob + 128 + lane] = x[ob + 128 + lane];
        out[ob + 192 + lane] = x[ob + 192 + lane];
        return;
    }

    const float4 dn = ((const float4*)denom)[d];
    const float i0 = 1.f / dn.x, i1 = 1.f / dn.y, i2 = 1.f / dn.z, i3 = 1.f / dn.w;

    float acc0 = 0.f, acc1 = 0.f, acc2 = 0.f, acc3 = 0.f;
    for (int base = 0; base < deg; base += 4) {
        const int m = deg - base;
        int eid[4]; float4 exv[4]; int ss[4];
#pragma unroll
        for (int j = 0; j < 4; j++) if (j < m) eid[j] = eidx[e0 + base + j];
#pragma unroll
        for (int j = 0; j < 4; j++) if (j < m) {
            exv[j] = ((const float4*)escore)[eid[j]];
            ss[j] = src[eid[j]];
        }
#pragma unroll
        for (int j = 0; j < 4; j++) if (j < m) {
            const float* hs = hfeat + (size_t)ss[j] * 256;
            acc0 += (exv[j].x * i0) * hs[lane];
            acc1 += (exv[j].y * i1) * hs[64 + lane];
            acc2 += (exv[j].z * i2) * hs[128 + lane];
            acc3 += (exv[j].w * i3) * hs[192 + lane];
        }
    }

    out[ob + lane]       = x[ob + lane]       + acc0;
    out[ob + 64 + lane]  = x[ob + 64 + lane]  + acc1;
    out[ob + 128 + lane] = x[ob + 128 + lane] + acc2;
    out[ob + 192 + lane] = x[ob + 192 + lane] + acc3;
}

extern "C" void kernel_launch(void* const* d_in, const int* in_sizes, int n_in,
                              void* d_out, int out_size, void* d_ws, size_t ws_size,
                              hipStream_t stream) {
    const float* x      = (const float*)d_in[0];
    const float* efeats = (const float*)d_in[1];
    const int*   src    = (const int*)d_in[2];
    const int*   dst    = (const int*)d_in[3];
    const float* Wni    = (const float*)d_in[4];
    const float* Wfij   = (const float*)d_in[5];
    const float* Wnj    = (const float*)d_in[6];
    const float* Wsrc   = (const float*)d_in[7];
    const float* attn   = (const float*)d_in[8];
    const float* bias   = (const float*)d_in[9];

    float* out  = (float*)d_out;                      // [N, 256]
    float* fout = out + (size_t)N_NODES * HFO;        // [E, 64]

    float* ws     = (float*)d_ws;
    float* xni    = ws;                                   // N*64
    float* xnj    = xni + (size_t)N_NODES * 64;           // N*64
    float* hfeat  = xnj + (size_t)N_NODES * 64;           // N*256
    float* escore = hfeat + (size_t)N_NODES * 256;        // E*4  (holds exp(e))
    float* denom  = escore + (size_t)N_EDGES * 4;         // N*4
    int*   cnt    = (int*)(denom + (size_t)N_NODES * 4);  // N
    int*   offs   = cnt + N_NODES;                        // N+1
    int*   cur    = offs + N_NODES + 1;                   // N
    int*   eidx   = cur + N_NODES;                        // E
    short* wpack  = (short*)(eidx + N_EDGES);             // 256*384 bf16

    // zero denom (N*4 floats) + cnt (N ints) in one contiguous memset
    hipMemsetAsync(denom, 0, (size_t)(N_NODES * 4 + N_NODES) * 4, stream);

    k_pack_w<<<(IN_F * NCOL + 255) / 256, 256, 0, stream>>>(Wni, Wnj, Wsrc, wpack);
    k1_mfma<<<(N_NODES + 63) / 64, 256, 0, stream>>>(x, wpack, xni, xnj, hfeat);
    k_count<<<(N_EDGES + 255) / 256, 256, 0, stream>>>(dst, cnt);
    k_scan<<<1, 1024, 0, stream>>>(cnt, offs, cur);
    k_fill<<<(N_EDGES + 255) / 256, 256, 0, stream>>>(dst, cur, eidx);
    k2_edge_mfma<<<2500, 256, 0, stream>>>(efeats, src, dst, Wfij, attn, bias,
                                           xni, xnj, fout, escore, denom);
    k5_gather<<<(N_NODES + 3) / 4, 256, 0, stream>>>(offs, eidx, src, escore, denom,
                                                     hfeat, x, out);
}